// Round 12
// baseline (438.076 us; speedup 1.0000x reference)
//
#include <hip/hip_runtime.h>
#include <hip/hip_bf16.h>
#include <stdint.h>

// Problem constants (fixed by setup_inputs)
#define NTOK   8192
#define TOPK   2
#define NEXP   8
#define DIN    2048
#define DOUT   2048
#define NK     (NTOK*TOPK)

// GEMM tiling: 256(M) x 128(N) tile, BK=32, 8 waves as 4(M) x 2(N),
// wave tile 64x64 = 4x4 MFMA 16x16x32 bf16 frags (the measured optimum:
// square wave tile minimizes LDS read duplication at 8 waves; R5/R9 closed
// the register/occupancy alternatives; R7 closed the 32x32 shape).
//
// ASYMMETRIC PREFETCH DEPTH (R11 design, rerun after infra failure): A is an
// indirect gather (scattered token rows, high latency variance); B is a
// sequential stream. A gets a depth-3 ring (NBUF_A=4), B depth-1 (NBUF_B=2).
// Feasible at 2 blocks/CU only because the sTok/sF LDS tables are eliminated
// (ssi re-read from global at setup/epilogue): LDS = 4*16K + 2*8K = 80 KiB,
// 2 x 80 KiB = exactly the 160 KiB pool.
#define BM 256
#define BN 128
#define BK 32
#define KTILES  (DIN/BK)           // 64
#define ASLOT   16384              // per-K-tile A: 256x32 bf16
#define BSLOT   8192               // per-K-tile B: 128x32 bf16
#define NBUFA   4                  // A ring: prefetch depth 3
#define NBUFB   2                  // B ring: prefetch depth 1
#define BOFF    (NBUFA*ASLOT)      // B region base = 65536

typedef __bf16 bf16_8 __attribute__((ext_vector_type(8)));  // 4 VGPRs, MFMA A/B frag
typedef float  f32x4  __attribute__((ext_vector_type(4)));  // MFMA C/D frag

// global->LDS direct load, 16B per lane. LDS dest = wave-uniform base + lane*16.
__device__ __forceinline__ void gl2lds16(const void* g, void* l) {
  auto gp = reinterpret_cast<const __attribute__((address_space(1))) uint32_t*>(
      reinterpret_cast<uintptr_t>(g));
  auto lp = reinterpret_cast<__attribute__((address_space(3))) uint32_t*>(
      reinterpret_cast<uintptr_t>(l));
  __builtin_amdgcn_global_load_lds(gp, lp, 16, 0, 0);
}

// Fused fp32 -> bf16 (RNE) for W then X. 8 elems/thread, 16B stores.
__global__ void cvt_all(const float4* __restrict__ w, uint4* __restrict__ wD,
                        const float4* __restrict__ x, uint4* __restrict__ xD,
                        int nW) {
  int b = blockIdx.x;
  const float4* src;
  uint4* dst;
  int i;
  if (b < nW) { src = w; dst = wD; i = b * 256 + threadIdx.x; }
  else        { src = x; dst = xD; i = (b - nW) * 256 + threadIdx.x; }
  float4 a0 = src[2 * i];
  float4 a1 = src[2 * i + 1];
  union { __bf16 h[8]; uint4 u; } r;
  r.h[0] = (__bf16)a0.x; r.h[1] = (__bf16)a0.y; r.h[2] = (__bf16)a0.z; r.h[3] = (__bf16)a0.w;
  r.h[4] = (__bf16)a1.x; r.h[5] = (__bf16)a1.y; r.h[6] = (__bf16)a1.z; r.h[7] = (__bf16)a1.w;
  dst[i] = r.u;
}

// Grouped GEMM over expert-sorted flat rows — R10 base + deep-A/shallow-B
// counted-vmcnt rings + XCD swizzle (FETCH 288 -> ~190 MB proven).
//
// Per K-tile t (ONE barrier, ONE counted wait):
//   stage B(t+1) -> bslot (t+1)&1   [1 gl2lds]   (issued FIRST)
//   stage A(t+3) -> aslot (t+3)&3   [2 gl2lds]   (issued after B)
//   ds_read af[0..3], bf[0..3] of tile t; 16 x MFMA 16x16x32
//   s_waitcnt vmcnt(2)   [A(t+1) done (3 tiles of cover for the gather) and
//                         B(t+1) done (1 tile ~1400cy >> L2 200cy); only
//                         A(t+3)'s 2 loads remain in flight]
//   s_barrier
// Tail: A-stage stops at t=KTILES-4, B-stage at t=KTILES-2; waits become
// vmcnt(0) for t in {KTILES-3, KTILES-2}; nothing after the last tile.
// WAR: A slot (t+3)&3 = (t-1)&3 and B slot (t+1)&1 = (t-1)&1 were last READ
// in tile t-1, whose ds_reads completed before that tile's closing barrier;
// both stages issue after it.
//
// LDS bank-conflict swizzle (measured 0 conflicts in this exact form):
// row r's 16B chunk q lives at chunk slot q ^ s(r), s(r) = (r>>1)&3.
// Staging lane loads global chunk (tid&3)^((tid>>3)&3); reader xors kq by
// (lr>>1)&3. s(r) invariant under r += multiples of 8.
__global__ __launch_bounds__(512, 4)
void moe_gemm(const __bf16* __restrict__ X,     // [NTOK, DIN] bf16
              const __bf16* __restrict__ W,     // [NEXP, DOUT, DIN] bf16 (B^T form)
              const int* __restrict__ ssi,      // sorted_scattered_idxs [NK]
              const int* __restrict__ offs,     // expert_offsets [NEXP]
              __bf16* __restrict__ flat)        // [NK, DOUT] bf16 out (ungated)
{
  __shared__ char lds[NBUFA * ASLOT + NBUFB * BSLOT];   // exactly 80 KiB

  const int tid = threadIdx.x;
  // XCD swizzle: HW assigns XCD = blockIdx % 8; remap so one XCD owns a
  // contiguous chunk of work ids -> same-mtg blocks share an L2. 1152%8==0.
  const int nwg = gridDim.x;
  const int b0  = blockIdx.x;
  const int bid = (b0 & 7) * (nwg >> 3) + (b0 >> 3);
  const int nt  = bid & 15;         // 16 N-tiles of 128
  const int mtg = bid >> 4;         // linear M-tile over all experts

  // Map linear M-tile -> (expert e, tile-in-segment). Uniform scan of 8 offsets.
  int start = 0, end = 0, e, cum = 0, prev = 0, mloc = 0, found = 0;
  for (e = 0; e < NEXP; ++e) {
    int oe  = offs[e];
    int seg = oe - prev;
    int t   = (seg + BM - 1) >> 8;
    if (mtg < cum + t) { start = prev; end = oe; mloc = mtg - cum; found = 1; break; }
    cum += t; prev = oe;
  }
  if (!found) return;  // pad block (uniform exit)

  const int m0 = start + mloc * BM;

  // Staging: thread tid owns A rows rs = tid>>2 and rs+128, B row rs,
  // swizzled k-chunk kc. Tokens read straight from ssi (no LDS tables);
  // clamp keeps the gather in-bounds, invalid rows discarded at epilogue.
  const int rs = tid >> 2;                       // 0..127
  const int kc = (tid & 3) ^ ((tid >> 3) & 3);   // swizzled chunk
  int p0 = m0 + rs, p1 = m0 + rs + 128;
  int tok0 = ssi[p0 < end ? p0 : (end - 1)] >> 1;
  int tok1 = ssi[p1 < end ? p1 : (end - 1)] >> 1;
  const __bf16* pA0 = X + (size_t)tok0 * DIN + kc * 8;
  const __bf16* pA1 = X + (size_t)tok1 * DIN + kc * 8;
  const __bf16* wBp = W + (size_t)e * DOUT * DIN + (size_t)(nt * BN) * DIN;
  const __bf16* pB0 = wBp + (size_t)rs * DIN + kc * 8;
  char* wsl = (char*)lds + (tid >> 6) * 1024;    // wave-uniform slice base

  // Prologue: B(0) first, then A tiles 0,1,2 (7 loads in flight per wave).
  gl2lds16(pB0, wsl + BOFF);
  pB0 += BK;
  gl2lds16(pA0, wsl);              gl2lds16(pA1, wsl + 8192);
  pA0 += BK; pA1 += BK;
  gl2lds16(pA0, wsl + ASLOT);      gl2lds16(pA1, wsl + ASLOT + 8192);
  pA0 += BK; pA1 += BK;
  gl2lds16(pA0, wsl + 2 * ASLOT);  gl2lds16(pA1, wsl + 2 * ASLOT + 8192);
  pA0 += BK; pA1 += BK;            // pA at tile 3, pB at tile 1

  // Fragment addressing. A frag: lane holds A[m=lr][k=kq*8+j]; LDS row = 64 B.
  const int w   = tid >> 6;
  const int l   = tid & 63;
  const int wm  = w >> 1, wn = w & 1;            // 4 x 2 wave grid
  const int lr  = l & 15;
  const int kq  = l >> 4;
  const int kqs = kq ^ ((lr >> 1) & 3);          // bank-conflict swizzle
  const char* aBase = (const char*)lds + (wm * 64 + lr) * 64 + kqs * 16;
  const char* bBase = (const char*)lds + BOFF + (wn * 64 + lr) * 64 + kqs * 16;

  // Tile 0 arrival: B(0)+A(0) done (A(1),A(2) may stay in flight).
  asm volatile("s_waitcnt vmcnt(4)" ::: "memory");
  __builtin_amdgcn_s_barrier();

  f32x4 acc[4][4] = {};

  for (int t = 0; t < KTILES; ++t) {
    // B(t+1) issued BEFORE A(t+3) so the end-of-tile vmcnt(2) covers both.
    if (t < KTILES - 1) {
      gl2lds16(pB0, wsl + BOFF + (((t + 1) & 1) << 13));
      pB0 += BK;
    }
    if (t < KTILES - 3) {
      char* d = wsl + (((t + 3) & 3) << 14);
      gl2lds16(pA0, d);  gl2lds16(pA1, d + 8192);
      pA0 += BK; pA1 += BK;
    }

    const char* aB = aBase + ((t & 3) << 14);
    const char* bB = bBase + ((t & 1) << 13);

    bf16_8 af[4], bf[4];
#pragma unroll
    for (int i = 0; i < 4; ++i) af[i] = *(const bf16_8*)(aB + i * 1024);  // rows i*16
#pragma unroll
    for (int i = 0; i < 4; ++i) bf[i] = *(const bf16_8*)(bB + i * 1024);  // cols i*16

#pragma unroll
    for (int am = 0; am < 4; ++am)
#pragma unroll
      for (int bn = 0; bn < 4; ++bn)
        acc[am][bn] = __builtin_amdgcn_mfma_f32_16x16x32_bf16(
            af[am], bf[bn], acc[am][bn], 0, 0, 0);

    // Arrival of tile t+1; never drain until the 2-tile tail.
    if (t < KTILES - 3)       { asm volatile("s_waitcnt vmcnt(2)" ::: "memory"); }
    else if (t < KTILES - 1)  { asm volatile("s_waitcnt vmcnt(0)" ::: "memory"); }
    if (t < KTILES - 1) __builtin_amdgcn_s_barrier();
  }

  // Epilogue: C/D layout col=lane&15, row=(lane>>4)*4+reg. Flat-index per
  // row read straight from ssi (L2-hot, 64 KB). Ungated bf16 stores.
  const int colBase = nt * BN + wn * 64 + lr;
  const int rq = kq * 4;
#pragma unroll
  for (int am = 0; am < 4; ++am) {
#pragma unroll
    for (int v = 0; v < 4; ++v) {
      int rl = wm * 64 + am * 16 + rq + v;
      int p  = m0 + rl;
      if (p >= end) continue;
      int f = ssi[p];
      __bf16* row = flat + (size_t)f * DOUT + colBase;
#pragma unroll
      for (int bn = 0; bn < 4; ++bn)
        row[bn * 16] = (__bf16)acc[am][bn][v];
    }
  }
}

// out[n, :] = g[2n]*flat[2n, :] + g[2n+1]*flat[2n+1, :]
__global__ __launch_bounds__(256)
void combine(const __bf16* __restrict__ flat, const float* __restrict__ gates,
             float* __restrict__ out) {
  const int n = blockIdx.x;
  const int c = threadIdx.x * 8;
  bf16_8 y0 = *(const bf16_8*)(flat + (size_t)(2 * n)     * DOUT + c);
  bf16_8 y1 = *(const bf16_8*)(flat + (size_t)(2 * n + 1) * DOUT + c);
  const float2 g = *(const float2*)(gates + 2 * n);
  float o[8];
#pragma unroll
  for (int j = 0; j < 8; ++j)
    o[j] = g.x * (float)y0[j] + g.y * (float)y1[j];
  float4* dst = (float4*)(out + (size_t)n * DOUT + c);
  dst[0] = *(float4*)&o[0];
  dst[1] = *(float4*)&o[4];
}

extern "C" void kernel_launch(void* const* d_in, const int* in_sizes, int n_in,
                              void* d_out, int out_size, void* d_ws, size_t ws_size,
                              hipStream_t stream) {
  const float* inputs = (const float*)d_in[0];   // [8192, 2048]
  const float* ew     = (const float*)d_in[1];   // [8, 2048, 2048] (E, out, in)
  const float* gates  = (const float*)d_in[2];   // [8192, 2]
  const int*   ssi    = (const int*)d_in[5];     // sorted_scattered_idxs [16384]
  const int*   offs   = (const int*)d_in[6];     // expert_offsets [8]
  float* out = (float*)d_out;

  // ws layout: bf16 W (64 MB) | bf16 X (32 MB) | bf16 flat out (64 MB)
  __bf16* wsW = (__bf16*)d_ws;
  __bf16* wsX = wsW + (size_t)NEXP * DOUT * DIN;
  __bf16* wsF = wsX + (size_t)NTOK * DIN;

  const int n8w = NEXP * DOUT * DIN / 8;   // 4194304 -> 16384 blocks
  const int n8x = NTOK * DIN / 8;          // 2097152 ->  8192 blocks
  const int nWb = n8w / 256, nXb = n8x / 256;
  cvt_all<<<nWb + nXb, 256, 0, stream>>>((const float4*)ew, (uint4*)wsW,
                                         (const float4*)inputs, (uint4*)wsX, nWb);

  // max M-tiles = 64 + 8 (per-expert ceil padding), 16 N-tiles of 128
  moe_gemm<<<72 * 16, 512, 0, stream>>>(wsX, wsW, ssi, offs, wsF);
  combine<<<NTOK, 256, 0, stream>>>(wsF, gates, out);
}